// Round 11
// baseline (136.774 us; speedup 1.0000x reference)
//
#include <hip/hip_runtime.h>
#include <hip/hip_bf16.h>
#include <math.h>

#define B_    8
#define C_    256
#define L_    4096
#define OCH_  256

typedef __attribute__((ext_vector_type(8)))  short bf16x8;
typedef __attribute__((ext_vector_type(16))) float f32x16;
typedef __attribute__((ext_vector_type(4)))  int   i32x4;

static __device__ __forceinline__ unsigned short bf16_rne(float f) {
    unsigned u = __float_as_uint(f);
    unsigned r = u + 0x7FFFu + ((u >> 16) & 1u);
    return (unsigned short)(r >> 16);
}

static __device__ __forceinline__ void gload_lds16(const void* g, void* l) {
    __builtin_amdgcn_global_load_lds(
        (const __attribute__((address_space(1))) unsigned int*)g,
        (__attribute__((address_space(3))) unsigned int*)l, 16, 0, 0);
}

// ---------------------------------------------------------------------------
// K0: pack W[o][c][k] -> Wpk[o][gran][0..7]=hi, [8..15]=lo
//     gran = k*32 + c/8 (96 granules of 8 consecutive c, k-major), e = c&7.
// ---------------------------------------------------------------------------
__global__ void k_split(const float* __restrict__ W,
                        unsigned short* __restrict__ Wpk) {
    int i = blockIdx.x * 256 + threadIdx.x;          // o*768 + c*3 + k
    if (i >= OCH_ * C_ * 3) return;
    int k = i % 3;
    int c = (i / 3) & 255;
    int o = i / 768;
    float w = W[i];
    unsigned short hb = bf16_rne(w);
    float hi = __uint_as_float((unsigned)hb << 16);
    unsigned short lb = bf16_rne(w - hi);
    int base = o * 1536 + (k * 32 + (c >> 3)) * 16 + (c & 7);
    Wpk[base]     = hb;
    Wpk[base + 8] = lb;
}

// ---------------------------------------------------------------------------
// K1: offset network, c-loop split across 2 wave-groups (32 loads/thread).
// Block 512 thr: (l, g, half). Partial h combined via LDS; half 0 finishes
// layer 2; wave 0 does softmax and emits window-form coef:
//   coef[(b*3+t)*L + l] = { d0, d1, bits(i0f2), 0 }
// ---------------------------------------------------------------------------
__global__ __launch_bounds__(512) void k_offsets(
        const float* __restrict__ x,
        const float* __restrict__ w1, const float* __restrict__ b1,
        const float* __restrict__ w2, const float* __restrict__ b2,
        float4* __restrict__ coef) {
    __shared__ float sH[2][4][16][65];               // 33.3 KB [half][g][o][l]
    __shared__ float sOm[64][37];                    // 9.25 KB
    int tid  = threadIdx.x;
    int l    = tid & 63;
    int g    = (tid >> 6) & 3;
    int half = tid >> 8;
    int blk  = blockIdx.x;
    int b    = blk & 7;                              // XCD affinity
    int l0   = (blk >> 3) << 6;
    int lg   = l0 + l;

    const float* xg = x + (size_t)b * C_ * L_ + (size_t)(g * 64 + half * 32) * L_ + lg;

    float h[16];
    #pragma unroll
    for (int o = 0; o < 16; ++o) h[o] = half ? 0.0f : b1[g * 16 + o];
    #pragma unroll 4
    for (int cg = 0; cg < 32; ++cg) {
        float xv = xg[(size_t)cg * L_];
        const float* w1p = w1 + (g * 16) * 64 + half * 32 + cg;
        #pragma unroll
        for (int o = 0; o < 16; ++o) h[o] = fmaf(xv, w1p[o * 64], h[o]);
    }
    #pragma unroll
    for (int o = 0; o < 16; ++o) sH[half][g][o][l] = h[o];
    __syncthreads();

    if (half == 0) {
        float om9[9];
        #pragma unroll
        for (int j = 0; j < 9; ++j) om9[j] = b2[g * 9 + j];
        #pragma unroll
        for (int o = 0; o < 16; ++o) {
            float a  = h[o] + sH[1][g][o][l];
            float hv = 0.5f * a * (1.0f + erff(a * 0.70710678118654752f));
            const float* w2p = w2 + g * 144 + o;     // w2[g][j][o]
            #pragma unroll
            for (int j = 0; j < 9; ++j) om9[j] = fmaf(hv, w2p[j * 16], om9[j]);
        }
        #pragma unroll
        for (int j = 0; j < 9; ++j) sOm[l][g * 9 + j] = om9[j];
    }
    __syncthreads();
    if (tid >= 64) return;

    float om[36];
    #pragma unroll
    for (int j = 0; j < 36; ++j) om[j] = sOm[tid][j];
    om[1] = 0.0f; om[3] = 0.0f; om[5] = 0.0f;
    float m = om[3];
    #pragma unroll
    for (int j = 4; j < 36; ++j) m = fmaxf(m, om[j]);
    float ssum = 0.0f;
    #pragma unroll
    for (int j = 3; j < 36; ++j) ssum += expf(om[j] - m);
    float inv = 1.0f / ssum;

    int lpos = l0 + tid;
    float base = -1.0f + 2.0f * (float)lpos / (float)(L_ - 1);
    #pragma unroll
    for (int t = 0; t < 3; ++t) {
        float mod  = expf(om[3 + t] - m) * inv;
        float off  = om[2 * t] * (2.0f / (float)L_);
        float grid = base + (-0.5f + 0.5f * (float)t) + off;
        float pp   = (grid + 1.0f) * 0.5f * (float)(L_ - 1);
        float fp   = floorf(pp);
        int i0 = (int)fp, i1 = i0 + 1;
        float w = pp - fp;
        float c0 = (i0 >= 0 && i0 < L_) ? (1.0f - w) * mod : 0.0f;
        float c1 = (i1 >= 0 && i1 < L_) ? w * mod : 0.0f;
        int i0c  = min(max(i0, 0), L_ - 1);
        int i1c  = min(max(i1, 0), L_ - 1);
        int i0f2 = min(max(i0, 0), L_ - 2);
        float d0 = (i0c == i0f2     ? c0 : 0.0f) + (i1c == i0f2     ? c1 : 0.0f);
        float d1 = (i0c == i0f2 + 1 ? c0 : 0.0f) + (i1c == i0f2 + 1 ? c1 : 0.0f);
        coef[((size_t)b * 3 + t) * L_ + lpos] =
            make_float4(d0, d1, __int_as_float(i0f2), 0.0f);
    }
}

// ---------------------------------------------------------------------------
// K2: materialize sampled matrix S, GEMM-blocked:
//   S[b][lt][s][l] : i32x4 = 8 bf16 for kk in [8s,8s+8), l-tile of 64.
// Thread handles 2 granules (s, s+48): 2 independent gather streams (ILP).
// ---------------------------------------------------------------------------
__global__ __launch_bounds__(256) void k_sample(
        const float* __restrict__ x, const float4* __restrict__ coef,
        i32x4* __restrict__ Sg) {
    int tid  = threadIdx.x;
    int l    = tid & 63;
    int unit = tid >> 6;                             // 0..3
    int bid  = blockIdx.x;
    int b    = bid & 7;                              // XCD affinity
    int r    = bid >> 3;
    int lt   = r & 63;
    int sg   = r >> 6;                               // 0..11
    int lgl  = lt * 64 + l;
    const float* xb = x + (size_t)b * C_ * L_;

    #pragma unroll
    for (int rep = 0; rep < 2; ++rep) {
        int s   = sg * 4 + unit + rep * 48;          // 0..95
        int tap = s >> 5;
        int c0  = s * 8 - tap * 256;
        float4 cf = coef[((size_t)b * 3 + tap) * L_ + lgl];
        float d0 = cf.x, d1 = cf.y;
        const float* xp = xb + (size_t)c0 * L_ + __float_as_int(cf.z);
        union { unsigned short us[8]; i32x4 v; } pk;
        #pragma unroll
        for (int e = 0; e < 8; ++e) {
            float g0 = xp[0], g1 = xp[1];
            pk.us[e] = bf16_rne(fmaf(g1, d1, g0 * d0));
            xp += L_;
        }
        Sg[((size_t)(b * 64 + lt) * 96 + s) * 64 + l] = pk.v;
    }
}

// ---------------------------------------------------------------------------
// K3: 2-pass split-precision MFMA GEMM, triple-buffered counted-vmcnt pipe,
// with UNSINKABLE batched A-loads (volatile + keep-alive asm).
// Granule pair j lives at shorts [j*32, j*32+8)=hi, [j*32+8, +8)=lo
// relative to wcs = WA + ch*256 + q*16  (q = k-half of the MFMA frag).
// Order per chunk: 16 volatile A-loads -> 2 gload_lds (S, ch+1) ->
// keep-alive -> s_waitcnt vmcnt(2) -> s_barrier -> 32 wait-free MFMAs.
// ---------------------------------------------------------------------------
__global__ __launch_bounds__(512, 4) void k_gemm(
        const unsigned short* __restrict__ Wpk,
        const float* __restrict__ bias,
        const i32x4* __restrict__ Sg,
        float* __restrict__ out) {
    __shared__ i32x4 sS[3][1024];                    // 48 KB

    const int tid  = threadIdx.x;
    const int lane = tid & 63;
    const int wv   = tid >> 6;                       // 0..7
    const int blk  = blockIdx.x;
    const int b    = blk & 7;                        // XCD affinity
    const int lt   = blk >> 3;
    const int l0   = lt * 64;
    const int q    = lane >> 5;
    const int l31  = lane & 31;

    const i32x4* Sblk = Sg + (size_t)(b * 64 + lt) * (96 * 64);
    const unsigned short* WA = Wpk + (size_t)(wv * 32 + l31) * 1536;

    f32x16 acc0, acc1;
    #pragma unroll
    for (int i = 0; i < 16; ++i) { acc0[i] = 0.f; acc1[i] = 0.f; }

    // prologue: stage chunk 0 into buffer 0
    gload_lds16(Sblk + tid,       &sS[0][tid]);
    gload_lds16(Sblk + 512 + tid, &sS[0][512 + tid]);

    #pragma unroll
    for (int ch = 0; ch < 6; ++ch) {
        const int br = ch % 3;
        const unsigned short* wcs = WA + ch * 256 + q * 16;  // short units

        // ---- batched, unsinkable A-loads (16 x 16B, volatile) ----
        // granule pair j: hi at shorts j*32, lo at j*32+8  (matches R9)
        #define VL(off) (*(const volatile bf16x8*)(wcs + (off)))
        bf16x8 ah0 = VL(0),   al0 = VL(8);
        bf16x8 ah1 = VL(32),  al1 = VL(40);
        bf16x8 ah2 = VL(64),  al2 = VL(72);
        bf16x8 ah3 = VL(96),  al3 = VL(104);
        bf16x8 ah4 = VL(128), al4 = VL(136);
        bf16x8 ah5 = VL(160), al5 = VL(168);
        bf16x8 ah6 = VL(192), al6 = VL(200);
        bf16x8 ah7 = VL(224), al7 = VL(232);
        #undef VL

        // ---- S prefetch for ch+1 (issued after A-loads) ----
        if (ch < 5) {
            const int bw = (ch + 1) % 3;
            const i32x4* src = Sblk + (ch + 1) * 1024;
            gload_lds16(src + tid,       &sS[bw][tid]);
            gload_lds16(src + 512 + tid, &sS[bw][512 + tid]);
        }

        // keep-alive: force all 16 A values materialized here (no sinking)
        asm volatile("" : "+v"(ah0), "+v"(al0), "+v"(ah1), "+v"(al1),
                          "+v"(ah2), "+v"(al2), "+v"(ah3), "+v"(al3),
                          "+v"(ah4), "+v"(al4), "+v"(ah5), "+v"(al5),
                          "+v"(ah6), "+v"(al6), "+v"(ah7), "+v"(al7));
        if (ch < 5) {
            asm volatile("s_waitcnt vmcnt(2)" ::: "memory");   // A + S(ch) done
        } else {
            asm volatile("s_waitcnt vmcnt(0)" ::: "memory");
        }
        __builtin_amdgcn_sched_barrier(0);
        __builtin_amdgcn_s_barrier();                // prefetch stays in flight
        __builtin_amdgcn_sched_barrier(0);

        #define KS_STEP(ks, AH, AL) {                                        \
            const i32x4* bp = &sS[br][((ks) * 2 + q) * 64 + l31];            \
            bf16x8 bh0 = *(const bf16x8*)bp;                                 \
            bf16x8 bh1 = *(const bf16x8*)(bp + 32);                          \
            __builtin_amdgcn_s_setprio(1);                                   \
            acc0 = __builtin_amdgcn_mfma_f32_32x32x16_bf16(AH, bh0, acc0, 0, 0, 0); \
            acc1 = __builtin_amdgcn_mfma_f32_32x32x16_bf16(AH, bh1, acc1, 0, 0, 0); \
            acc0 = __builtin_amdgcn_mfma_f32_32x32x16_bf16(AL, bh0, acc0, 0, 0, 0); \
            acc1 = __builtin_amdgcn_mfma_f32_32x32x16_bf16(AL, bh1, acc1, 0, 0, 0); \
            __builtin_amdgcn_s_setprio(0);                                   \
        }
        KS_STEP(0, ah0, al0)
        KS_STEP(1, ah1, al1)
        KS_STEP(2, ah2, al2)
        KS_STEP(3, ah3, al3)
        KS_STEP(4, ah4, al4)
        KS_STEP(5, ah5, al5)
        KS_STEP(6, ah6, al6)
        KS_STEP(7, ah7, al7)
        #undef KS_STEP
    }

    // epilogue: bias + store. D: col=lane&31, row=(reg&3)+8*(reg>>2)+4*q
    #pragma unroll
    for (int reg = 0; reg < 16; ++reg) {
        int rr = (reg & 3) + 8 * (reg >> 2) + 4 * q;
        int o  = wv * 32 + rr;
        float bv = bias[o];
        float* op = out + ((size_t)b * 256 + o) * L_ + l0 + l31;
        op[0]  = acc0[reg] + bv;
        op[32] = acc1[reg] + bv;
    }
}

// ---------------------------------------------------------------------------
extern "C" void kernel_launch(void* const* d_in, const int* in_sizes, int n_in,
                              void* d_out, int out_size, void* d_ws, size_t ws_size,
                              hipStream_t stream) {
    const float* x      = (const float*)d_in[0];
    const float* weight = (const float*)d_in[1];
    const float* bias   = (const float*)d_in[2];
    const float* w1     = (const float*)d_in[3];
    const float* b1     = (const float*)d_in[4];
    const float* w2     = (const float*)d_in[5];
    const float* b2     = (const float*)d_in[6];
    float* out = (float*)d_out;

    const size_t COEF_B = (size_t)B_ * 3 * L_ * sizeof(float4);   // 1.5 MB
    const size_t W_B    = (size_t)OCH_ * 1536 * 2;                // 768 KB
    char* ws = (char*)d_ws;
    float4*         coef = (float4*)ws;
    unsigned short* Wpk  = (unsigned short*)(ws + COEF_B);
    i32x4*          Sg   = (i32x4*)(ws + COEF_B + W_B);           // 48 MB

    k_split<<<(OCH_ * C_ * 3 + 255) / 256, 256, 0, stream>>>(weight, Wpk);
    k_offsets<<<B_ * (L_ / 64), 512, 0, stream>>>(x, w1, b1, w2, b2, coef);
    k_sample<<<B_ * 64 * 12, 256, 0, stream>>>(x, coef, Sg);
    k_gemm<<<B_ * (L_ / 64), 512, 0, stream>>>(Wpk, bias, Sg, out);
}

// Round 13
// 88.649 us; speedup vs baseline: 1.5429x; 1.5429x over previous
//
#include <hip/hip_runtime.h>
#include <hip/hip_bf16.h>
#include <math.h>

#define B_    8
#define C_    256
#define L_    4096
#define OCH_  256

typedef __attribute__((ext_vector_type(8)))  short bf16x8;
typedef __attribute__((ext_vector_type(16))) float f32x16;
typedef __attribute__((ext_vector_type(4)))  int   i32x4;

static __device__ __forceinline__ unsigned short bf16_rne(float f) {
    unsigned u = __float_as_uint(f);
    unsigned r = u + 0x7FFFu + ((u >> 16) & 1u);
    return (unsigned short)(r >> 16);
}

static __device__ __forceinline__ void gload_lds16(const void* g, void* l) {
    __builtin_amdgcn_global_load_lds(
        (const __attribute__((address_space(1))) unsigned int*)g,
        (__attribute__((address_space(3))) unsigned int*)l, 16, 0, 0);
}

// ---------------------------------------------------------------------------
// K0: W[o][c][k] -> k-major bf16: Wb[o][k*256+c]  (single pass, RNE)
// ---------------------------------------------------------------------------
__global__ void k_split(const float* __restrict__ W,
                        unsigned short* __restrict__ Wb) {
    int i = blockIdx.x * 256 + threadIdx.x;          // o*768 + c*3 + k
    if (i >= OCH_ * C_ * 3) return;
    int k = i % 3;
    int c = (i / 3) & 255;
    int o = i / 768;
    Wb[o * 768 + k * 256 + c] = bf16_rne(W[i]);
}

// ---------------------------------------------------------------------------
// K1: offset network, c-loop split across 2 wave-groups (32 loads/thread).
// Block 512 thr: (l, g, half). Partial h combined via LDS; half 0 finishes
// layer 2; wave 0 does softmax and emits window-form coef:
//   coef[(b*3+t)*L + l] = { d0, d1, bits(i0f2), 0 }
// ---------------------------------------------------------------------------
__global__ __launch_bounds__(512) void k_offsets(
        const float* __restrict__ x,
        const float* __restrict__ w1, const float* __restrict__ b1,
        const float* __restrict__ w2, const float* __restrict__ b2,
        float4* __restrict__ coef) {
    __shared__ float sH[2][4][16][65];               // 33.3 KB [half][g][o][l]
    __shared__ float sOm[64][37];                    // 9.25 KB
    int tid  = threadIdx.x;
    int l    = tid & 63;
    int g    = (tid >> 6) & 3;
    int half = tid >> 8;
    int blk  = blockIdx.x;
    int b    = blk & 7;                              // XCD affinity
    int l0   = (blk >> 3) << 6;
    int lg   = l0 + l;

    const float* xg = x + (size_t)b * C_ * L_ + (size_t)(g * 64 + half * 32) * L_ + lg;

    float h[16];
    #pragma unroll
    for (int o = 0; o < 16; ++o) h[o] = half ? 0.0f : b1[g * 16 + o];
    #pragma unroll 4
    for (int cg = 0; cg < 32; ++cg) {
        float xv = xg[(size_t)cg * L_];
        const float* w1p = w1 + (g * 16) * 64 + half * 32 + cg;
        #pragma unroll
        for (int o = 0; o < 16; ++o) h[o] = fmaf(xv, w1p[o * 64], h[o]);
    }
    #pragma unroll
    for (int o = 0; o < 16; ++o) sH[half][g][o][l] = h[o];
    __syncthreads();

    if (half == 0) {
        float om9[9];
        #pragma unroll
        for (int j = 0; j < 9; ++j) om9[j] = b2[g * 9 + j];
        #pragma unroll
        for (int o = 0; o < 16; ++o) {
            float a  = h[o] + sH[1][g][o][l];
            float hv = 0.5f * a * (1.0f + erff(a * 0.70710678118654752f));
            const float* w2p = w2 + g * 144 + o;     // w2[g][j][o]
            #pragma unroll
            for (int j = 0; j < 9; ++j) om9[j] = fmaf(hv, w2p[j * 16], om9[j]);
        }
        #pragma unroll
        for (int j = 0; j < 9; ++j) sOm[l][g * 9 + j] = om9[j];
    }
    __syncthreads();
    if (tid >= 64) return;

    float om[36];
    #pragma unroll
    for (int j = 0; j < 36; ++j) om[j] = sOm[tid][j];
    om[1] = 0.0f; om[3] = 0.0f; om[5] = 0.0f;
    float m = om[3];
    #pragma unroll
    for (int j = 4; j < 36; ++j) m = fmaxf(m, om[j]);
    float ssum = 0.0f;
    #pragma unroll
    for (int j = 3; j < 36; ++j) ssum += expf(om[j] - m);
    float inv = 1.0f / ssum;

    int lpos = l0 + tid;
    float base = -1.0f + 2.0f * (float)lpos / (float)(L_ - 1);
    #pragma unroll
    for (int t = 0; t < 3; ++t) {
        float mod  = expf(om[3 + t] - m) * inv;
        float off  = om[2 * t] * (2.0f / (float)L_);
        float grid = base + (-0.5f + 0.5f * (float)t) + off;
        float pp   = (grid + 1.0f) * 0.5f * (float)(L_ - 1);
        float fp   = floorf(pp);
        int i0 = (int)fp, i1 = i0 + 1;
        float w = pp - fp;
        float c0 = (i0 >= 0 && i0 < L_) ? (1.0f - w) * mod : 0.0f;
        float c1 = (i1 >= 0 && i1 < L_) ? w * mod : 0.0f;
        int i0c  = min(max(i0, 0), L_ - 1);
        int i1c  = min(max(i1, 0), L_ - 1);
        int i0f2 = min(max(i0, 0), L_ - 2);
        float d0 = (i0c == i0f2     ? c0 : 0.0f) + (i1c == i0f2     ? c1 : 0.0f);
        float d1 = (i0c == i0f2 + 1 ? c0 : 0.0f) + (i1c == i0f2 + 1 ? c1 : 0.0f);
        coef[((size_t)b * 3 + t) * L_ + lpos] =
            make_float4(d0, d1, __int_as_float(i0f2), 0.0f);
    }
}

// ---------------------------------------------------------------------------
// K2: materialize sampled matrix S, GEMM-blocked:
//   S[b][lt][s][l] : i32x4 = 8 bf16 for kk in [8s,8s+8), l-tile of 64.
// Thread handles 2 granules (s, s+48): 2 independent gather streams (ILP).
// ---------------------------------------------------------------------------
__global__ __launch_bounds__(256) void k_sample(
        const float* __restrict__ x, const float4* __restrict__ coef,
        i32x4* __restrict__ Sg) {
    int tid  = threadIdx.x;
    int l    = tid & 63;
    int unit = tid >> 6;                             // 0..3
    int bid  = blockIdx.x;
    int b    = bid & 7;                              // XCD affinity
    int r    = bid >> 3;
    int lt   = r & 63;
    int sg   = r >> 6;                               // 0..11
    int lgl  = lt * 64 + l;
    const float* xb = x + (size_t)b * C_ * L_;

    #pragma unroll
    for (int rep = 0; rep < 2; ++rep) {
        int s   = sg * 4 + unit + rep * 48;          // 0..95
        int tap = s >> 5;
        int c0  = s * 8 - tap * 256;
        float4 cf = coef[((size_t)b * 3 + tap) * L_ + lgl];
        float d0 = cf.x, d1 = cf.y;
        const float* xp = xb + (size_t)c0 * L_ + __float_as_int(cf.z);
        union { unsigned short us[8]; i32x4 v; } pk;
        #pragma unroll
        for (int e = 0; e < 8; ++e) {
            float g0 = xp[0], g1 = xp[1];
            pk.us[e] = bf16_rne(fmaf(g1, d1, g0 * d0));
            xp += L_;
        }
        Sg[((size_t)(b * 64 + lt) * 96 + s) * 64 + l] = pk.v;
    }
}

// ---------------------------------------------------------------------------
// K3: 1-pass bf16 MFMA GEMM, register-pipelined A, depth-2 S prefetch.
// Block 512 thr (8 waves) -> 256o x 64l; wave wv owns o-rows wv*32..+32.
// Per chunk ch: issue A(ch+1) regs (8x16B) -> keepalive -> vmcnt(8)
// [A(ch),S(ch) complete; A(ch+1) in flight] -> s_barrier ->
// gload S(ch+2) POST-barrier (3-buffer WAR-safe: all waves finished
// reading (ch-1)%3 before any wave can issue into (ch+2)%3=(ch-1)%3) ->
// 16 MFMAs from registers + LDS.
// ---------------------------------------------------------------------------
__global__ __launch_bounds__(512, 4) void k_gemm(
        const unsigned short* __restrict__ Wb,
        const float* __restrict__ bias,
        const i32x4* __restrict__ Sg,
        float* __restrict__ out) {
    __shared__ i32x4 sS[3][1024];                    // 48 KB

    const int tid  = threadIdx.x;
    const int lane = tid & 63;
    const int wv   = tid >> 6;                       // 0..7
    const int blk  = blockIdx.x;
    const int b    = blk & 7;                        // XCD affinity
    const int lt   = blk >> 3;
    const int l0   = lt * 64;
    const int q    = lane >> 5;
    const int l31  = lane & 31;

    const i32x4* Sblk = Sg + (size_t)(b * 64 + lt) * (96 * 64);
    const unsigned short* WA = Wb + (size_t)(wv * 32 + l31) * 768 + q * 8;

    f32x16 acc0, acc1;
    #pragma unroll
    for (int i = 0; i < 16; ++i) { acc0[i] = 0.f; acc1[i] = 0.f; }

    bf16x8 aP[8], aQ[8];

    // prologue: A(0) regs, S(0)+S(1) into buffers 0,1
    #pragma unroll
    for (int j = 0; j < 8; ++j)
        aP[j] = *(const bf16x8*)(WA + j * 16);
    gload_lds16(Sblk + tid,        &sS[0][tid]);
    gload_lds16(Sblk + 512 + tid,  &sS[0][512 + tid]);
    gload_lds16(Sblk + 1024 + tid, &sS[1][tid]);
    gload_lds16(Sblk + 1536 + tid, &sS[1][512 + tid]);

    #pragma unroll
    for (int ch = 0; ch < 6; ++ch) {
        const int br = ch % 3;

        // ---- issue next-chunk A-loads (stay in flight across the wait) ----
        if (ch < 5) {
            const unsigned short* wn = WA + (ch + 1) * 128;
            #pragma unroll
            for (int j = 0; j < 8; ++j)
                aQ[j] = *(const bf16x8*)(wn + j * 16);
            asm volatile("" : "+v"(aQ[0]), "+v"(aQ[1]), "+v"(aQ[2]), "+v"(aQ[3]),
                              "+v"(aQ[4]), "+v"(aQ[5]), "+v"(aQ[6]), "+v"(aQ[7]));
        }
        __builtin_amdgcn_sched_barrier(0);

        // ---- wait: everything older than the 8 A(ch+1) loads = A(ch),S(ch) ----
        if (ch < 5) asm volatile("s_waitcnt vmcnt(8)" ::: "memory");
        else        asm volatile("s_waitcnt vmcnt(0)" ::: "memory");
        __builtin_amdgcn_sched_barrier(0);
        __builtin_amdgcn_s_barrier();
        __builtin_amdgcn_sched_barrier(0);

        // ---- S prefetch depth-2, post-barrier (WAR-safe with 3 buffers) ----
        if (ch < 4) {
            const int bw = (ch + 2) % 3;
            const i32x4* src = Sblk + (ch + 2) * 1024;
            gload_lds16(src + tid,       &sS[bw][tid]);
            gload_lds16(src + 512 + tid, &sS[bw][512 + tid]);
        }
        __builtin_amdgcn_sched_barrier(0);

        // ---- MFMA phase: 16 MFMAs, A from registers, B from LDS ----
        #pragma unroll
        for (int ks = 0; ks < 8; ++ks) {
            const i32x4* bp = &sS[br][(ks * 2 + q) * 64 + l31];
            bf16x8 bh0 = *(const bf16x8*)bp;
            bf16x8 bh1 = *(const bf16x8*)(bp + 32);
            __builtin_amdgcn_s_setprio(1);
            acc0 = __builtin_amdgcn_mfma_f32_32x32x16_bf16(aP[ks], bh0, acc0, 0, 0, 0);
            acc1 = __builtin_amdgcn_mfma_f32_32x32x16_bf16(aP[ks], bh1, acc1, 0, 0, 0);
            __builtin_amdgcn_s_setprio(0);
        }

        // ---- rotate A registers ----
        if (ch < 5) {
            #pragma unroll
            for (int j = 0; j < 8; ++j) aP[j] = aQ[j];
        }
    }

    // epilogue: bias + store. D: col=lane&31, row=(reg&3)+8*(reg>>2)+4*q
    #pragma unroll
    for (int reg = 0; reg < 16; ++reg) {
        int rr = (reg & 3) + 8 * (reg >> 2) + 4 * q;
        int o  = wv * 32 + rr;
        float bv = bias[o];
        float* op = out + ((size_t)b * 256 + o) * L_ + l0 + l31;
        op[0]  = acc0[reg] + bv;
        op[32] = acc1[reg] + bv;
    }
}

// ---------------------------------------------------------------------------
extern "C" void kernel_launch(void* const* d_in, const int* in_sizes, int n_in,
                              void* d_out, int out_size, void* d_ws, size_t ws_size,
                              hipStream_t stream) {
    const float* x      = (const float*)d_in[0];
    const float* weight = (const float*)d_in[1];
    const float* bias   = (const float*)d_in[2];
    const float* w1     = (const float*)d_in[3];
    const float* b1     = (const float*)d_in[4];
    const float* w2     = (const float*)d_in[5];
    const float* b2     = (const float*)d_in[6];
    float* out = (float*)d_out;

    const size_t COEF_B = (size_t)B_ * 3 * L_ * sizeof(float4);   // 1.5 MB
    const size_t W_B    = (size_t)OCH_ * 768 * 2;                 // 384 KB
    char* ws = (char*)d_ws;
    float4*         coef = (float4*)ws;
    unsigned short* Wb   = (unsigned short*)(ws + COEF_B);
    i32x4*          Sg   = (i32x4*)(ws + COEF_B + W_B);           // 48 MB

    k_split<<<(OCH_ * C_ * 3 + 255) / 256, 256, 0, stream>>>(weight, Wb);
    k_offsets<<<B_ * (L_ / 64), 512, 0, stream>>>(x, w1, b1, w2, b2, coef);
    k_sample<<<B_ * 64 * 12, 256, 0, stream>>>(x, coef, Sg);
    k_gemm<<<B_ * (L_ / 64), 512, 0, stream>>>(Wb, bias, Sg, out);
}

// Round 14
// 76.270 us; speedup vs baseline: 1.7933x; 1.1623x over previous
//
#include <hip/hip_runtime.h>
#include <hip/hip_bf16.h>
#include <math.h>

#define B_    8
#define C_    256
#define L_    4096
#define OCH_  256

typedef __attribute__((ext_vector_type(8)))  short bf16x8;
typedef __attribute__((ext_vector_type(16))) float f32x16;
typedef __attribute__((ext_vector_type(4)))  int   i32x4;

static __device__ __forceinline__ unsigned short bf16_rne(float f) {
    unsigned u = __float_as_uint(f);
    unsigned r = u + 0x7FFFu + ((u >> 16) & 1u);
    return (unsigned short)(r >> 16);
}

static __device__ __forceinline__ void gload_lds16(const void* g, void* l) {
    __builtin_amdgcn_global_load_lds(
        (const __attribute__((address_space(1))) unsigned int*)g,
        (__attribute__((address_space(3))) unsigned int*)l, 16, 0, 0);
}

// ---------------------------------------------------------------------------
// K1: offset network + (fused) weight split.
// Split prologue: tid<384 converts W[o][c][k] -> k-major bf16 Wb[o][k*256+c].
// Then: c-loop split across 2 wave-groups; LDS combine; wave 0 softmax ->
// window-form coef[(b*3+t)*L + l] = { d0, d1, bits(i0f2), 0 }.
// ---------------------------------------------------------------------------
__global__ __launch_bounds__(512) void k_offsets(
        const float* __restrict__ x,
        const float* __restrict__ w1, const float* __restrict__ b1,
        const float* __restrict__ w2, const float* __restrict__ b2,
        const float* __restrict__ W,  unsigned short* __restrict__ Wb,
        float4* __restrict__ coef) {
    __shared__ float sH[2][4][16][65];               // 33.3 KB [half][g][o][l]
    __shared__ float sOm[64][37];                    // 9.25 KB
    int tid  = threadIdx.x;
    int blk  = blockIdx.x;

    // ---- fused weight split: 384 elements per block (512 blocks) ----
    if (tid < 384) {
        int i = blk * 384 + tid;                     // o*768 + c*3 + k
        int k = i % 3;
        int c = (i / 3) & 255;
        int o = i / 768;
        Wb[o * 768 + k * 256 + c] = bf16_rne(W[i]);
    }

    int l    = tid & 63;
    int g    = (tid >> 6) & 3;
    int half = tid >> 8;
    int b    = blk & 7;                              // XCD affinity
    int l0   = (blk >> 3) << 6;
    int lg   = l0 + l;

    const float* xg = x + (size_t)b * C_ * L_ + (size_t)(g * 64 + half * 32) * L_ + lg;

    float h[16];
    #pragma unroll
    for (int o = 0; o < 16; ++o) h[o] = half ? 0.0f : b1[g * 16 + o];
    #pragma unroll 4
    for (int cg = 0; cg < 32; ++cg) {
        float xv = xg[(size_t)cg * L_];
        const float* w1p = w1 + (g * 16) * 64 + half * 32 + cg;
        #pragma unroll
        for (int o = 0; o < 16; ++o) h[o] = fmaf(xv, w1p[o * 64], h[o]);
    }
    #pragma unroll
    for (int o = 0; o < 16; ++o) sH[half][g][o][l] = h[o];
    __syncthreads();

    if (half == 0) {
        float om9[9];
        #pragma unroll
        for (int j = 0; j < 9; ++j) om9[j] = b2[g * 9 + j];
        #pragma unroll
        for (int o = 0; o < 16; ++o) {
            float a  = h[o] + sH[1][g][o][l];
            float hv = 0.5f * a * (1.0f + erff(a * 0.70710678118654752f));
            const float* w2p = w2 + g * 144 + o;     // w2[g][j][o]
            #pragma unroll
            for (int j = 0; j < 9; ++j) om9[j] = fmaf(hv, w2p[j * 16], om9[j]);
        }
        #pragma unroll
        for (int j = 0; j < 9; ++j) sOm[l][g * 9 + j] = om9[j];
    }
    __syncthreads();
    if (tid >= 64) return;

    float om[36];
    #pragma unroll
    for (int j = 0; j < 36; ++j) om[j] = sOm[tid][j];
    om[1] = 0.0f; om[3] = 0.0f; om[5] = 0.0f;
    float m = om[3];
    #pragma unroll
    for (int j = 4; j < 36; ++j) m = fmaxf(m, om[j]);
    float ssum = 0.0f;
    #pragma unroll
    for (int j = 3; j < 36; ++j) ssum += expf(om[j] - m);
    float inv = 1.0f / ssum;

    int lpos = l0 + tid;
    float base = -1.0f + 2.0f * (float)lpos / (float)(L_ - 1);
    #pragma unroll
    for (int t = 0; t < 3; ++t) {
        float mod  = expf(om[3 + t] - m) * inv;
        float off  = om[2 * t] * (2.0f / (float)L_);
        float grid = base + (-0.5f + 0.5f * (float)t) + off;
        float pp   = (grid + 1.0f) * 0.5f * (float)(L_ - 1);
        float fp   = floorf(pp);
        int i0 = (int)fp, i1 = i0 + 1;
        float w = pp - fp;
        float c0 = (i0 >= 0 && i0 < L_) ? (1.0f - w) * mod : 0.0f;
        float c1 = (i1 >= 0 && i1 < L_) ? w * mod : 0.0f;
        int i0c  = min(max(i0, 0), L_ - 1);
        int i1c  = min(max(i1, 0), L_ - 1);
        int i0f2 = min(max(i0, 0), L_ - 2);
        float d0 = (i0c == i0f2     ? c0 : 0.0f) + (i1c == i0f2     ? c1 : 0.0f);
        float d1 = (i0c == i0f2 + 1 ? c0 : 0.0f) + (i1c == i0f2 + 1 ? c1 : 0.0f);
        coef[((size_t)b * 3 + t) * L_ + lpos] =
            make_float4(d0, d1, __int_as_float(i0f2), 0.0f);
    }
}

// ---------------------------------------------------------------------------
// K2: materialize sampled matrix S, GEMM-blocked for 128-l tiles:
//   S[b][lt(32)][s(96)][l(128)] : i32x4 = 8 bf16 for kk in [8s,8s+8).
// Thread = one granule: 8 gathers -> pack -> 1 dwordx4 store.
// ---------------------------------------------------------------------------
__global__ __launch_bounds__(512) void k_sample(
        const float* __restrict__ x, const float4* __restrict__ coef,
        i32x4* __restrict__ Sg) {
    int tid  = threadIdx.x;
    int l    = tid & 127;
    int unit = tid >> 7;                             // 0..3
    int bid  = blockIdx.x;
    int b    = bid & 7;                              // XCD affinity
    int r    = bid >> 3;                             // 0..767
    int lt   = r & 31;
    int sg   = r >> 5;                               // 0..23
    int s    = sg * 4 + unit;                        // 0..95
    int tap  = s >> 5;
    int c0   = s * 8 - tap * 256;
    int lgl  = lt * 128 + l;
    const float* xb = x + (size_t)b * C_ * L_;

    float4 cf = coef[((size_t)b * 3 + tap) * L_ + lgl];
    float d0 = cf.x, d1 = cf.y;
    const float* xp = xb + (size_t)c0 * L_ + __float_as_int(cf.z);
    union { unsigned short us[8]; i32x4 v; } pk;
    #pragma unroll
    for (int e = 0; e < 8; ++e) {
        float g0 = xp[0], g1 = xp[1];
        pk.us[e] = bf16_rne(fmaf(g1, d1, g0 * d0));
        xp += L_;
    }
    Sg[((size_t)(b * 32 + lt) * 96 + s) * 128 + l] = pk.v;
}

// ---------------------------------------------------------------------------
// K3: 1-pass bf16 MFMA GEMM. Tile 256o x 128l, grid 256 (1 block/CU).
// Block 512 thr (8 waves); wave wv owns o-rows wv*32..+32, all 128 cols
// (nf=4). K=768, chunk 64 (12 chunks), 2-buffer LDS.
// Per chunk: plain-issue A(ch+1) -> sched_barrier -> vmcnt(4)
// [A(ch),S(ch) done; A(ch+1) in flight] -> s_barrier -> issue S(ch+1)
// post-barrier (WAR-safe: every wave passed the barrier => finished
// reading buf^1) -> 16 MFMAs. NO keep-alive asm (it forces a drain).
// ---------------------------------------------------------------------------
__global__ __launch_bounds__(512, 4) void k_gemm(
        const unsigned short* __restrict__ Wb,
        const float* __restrict__ bias,
        const i32x4* __restrict__ Sg,
        float* __restrict__ out) {
    __shared__ i32x4 sS[2][8][128];                  // 32 KB

    const int tid  = threadIdx.x;
    const int lane = tid & 63;
    const int wv   = tid >> 6;                       // 0..7
    const int blk  = blockIdx.x;
    const int b    = blk & 7;                        // XCD affinity
    const int lt   = blk >> 3;                       // 0..31
    const int l0   = lt * 128;
    const int q    = lane >> 5;
    const int l31  = lane & 31;

    const i32x4* Sblk = Sg + (size_t)(b * 32 + lt) * (96 * 128);
    const unsigned short* WA = Wb + (size_t)(wv * 32 + l31) * 768 + q * 8;

    f32x16 acc0, acc1, acc2, acc3;
    #pragma unroll
    for (int i = 0; i < 16; ++i) { acc0[i] = 0.f; acc1[i] = 0.f; acc2[i] = 0.f; acc3[i] = 0.f; }

    bf16x8 aP0, aP1, aP2, aP3, aQ0, aQ1, aQ2, aQ3;

    // prologue: A(0) regs, S(0) into buffer 0
    aP0 = *(const bf16x8*)(WA);
    aP1 = *(const bf16x8*)(WA + 16);
    aP2 = *(const bf16x8*)(WA + 32);
    aP3 = *(const bf16x8*)(WA + 48);
    gload_lds16(Sblk + tid,       &sS[0][0][0] + tid);
    gload_lds16(Sblk + 512 + tid, &sS[0][0][0] + 512 + tid);

    #pragma unroll
    for (int ch = 0; ch < 12; ++ch) {
        const int buf = ch & 1;

        // ---- issue A(ch+1) (plain loads; sched_barrier pins issue here) ----
        if (ch < 11) {
            const unsigned short* wn = WA + (ch + 1) * 64;
            aQ0 = *(const bf16x8*)(wn);
            aQ1 = *(const bf16x8*)(wn + 16);
            aQ2 = *(const bf16x8*)(wn + 32);
            aQ3 = *(const bf16x8*)(wn + 48);
        }
        __builtin_amdgcn_sched_barrier(0);

        // ---- counted wait: A(ch)+S(ch) complete, A(ch+1) stays in flight ----
        if (ch < 11) asm volatile("s_waitcnt vmcnt(4)" ::: "memory");
        else         asm volatile("s_waitcnt vmcnt(0)" ::: "memory");
        __builtin_amdgcn_sched_barrier(0);
        __builtin_amdgcn_s_barrier();
        __builtin_amdgcn_sched_barrier(0);

        // ---- S(ch+1) prefetch post-barrier (2-buffer WAR-safe) ----
        if (ch < 11) {
            const i32x4* src = Sblk + (ch + 1) * 1024;
            gload_lds16(src + tid,       &sS[buf ^ 1][0][0] + tid);
            gload_lds16(src + 512 + tid, &sS[buf ^ 1][0][0] + 512 + tid);
        }
        __builtin_amdgcn_sched_barrier(0);

        // ---- MFMA phase: 4 ks x 4 nf ----
        #define KS_STEP(ks, AP) {                                            \
            const i32x4* bp = &sS[buf][(ks) * 2 + q][l31];                   \
            bf16x8 b0 = *(const bf16x8*)(bp);                                \
            bf16x8 b1 = *(const bf16x8*)(bp + 32);                           \
            bf16x8 b2 = *(const bf16x8*)(bp + 64);                           \
            bf16x8 b3 = *(const bf16x8*)(bp + 96);                           \
            __builtin_amdgcn_s_setprio(1);                                   \
            acc0 = __builtin_amdgcn_mfma_f32_32x32x16_bf16(AP, b0, acc0, 0, 0, 0); \
            acc1 = __builtin_amdgcn_mfma_f32_32x32x16_bf16(AP, b1, acc1, 0, 0, 0); \
            acc2 = __builtin_amdgcn_mfma_f32_32x32x16_bf16(AP, b2, acc2, 0, 0, 0); \
            acc3 = __builtin_amdgcn_mfma_f32_32x32x16_bf16(AP, b3, acc3, 0, 0, 0); \
            __builtin_amdgcn_s_setprio(0);                                   \
        }
        KS_STEP(0, aP0)
        KS_STEP(1, aP1)
        KS_STEP(2, aP2)
        KS_STEP(3, aP3)
        #undef KS_STEP

        // ---- rotate A registers ----
        if (ch < 11) { aP0 = aQ0; aP1 = aQ1; aP2 = aQ2; aP3 = aQ3; }
    }

    // epilogue: bias + store. D: col=lane&31, row=(reg&3)+8*(reg>>2)+4*q
    #pragma unroll
    for (int reg = 0; reg < 16; ++reg) {
        int rr = (reg & 3) + 8 * (reg >> 2) + 4 * q;
        int o  = wv * 32 + rr;
        float bv = bias[o];
        float* op = out + ((size_t)b * 256 + o) * L_ + l0 + l31;
        op[0]  = acc0[reg] + bv;
        op[32] = acc1[reg] + bv;
        op[64] = acc2[reg] + bv;
        op[96] = acc3[reg] + bv;
    }
}

// ---------------------------------------------------------------------------
extern "C" void kernel_launch(void* const* d_in, const int* in_sizes, int n_in,
                              void* d_out, int out_size, void* d_ws, size_t ws_size,
                              hipStream_t stream) {
    const float* x      = (const float*)d_in[0];
    const float* weight = (const float*)d_in[1];
    const float* bias   = (const float*)d_in[2];
    const float* w1     = (const float*)d_in[3];
    const float* b1     = (const float*)d_in[4];
    const float* w2     = (const float*)d_in[5];
    const float* b2     = (const float*)d_in[6];
    float* out = (float*)d_out;

    const size_t COEF_B = (size_t)B_ * 3 * L_ * sizeof(float4);   // 1.5 MB
    const size_t W_B    = (size_t)OCH_ * 768 * 2;                 // 384 KB
    char* ws = (char*)d_ws;
    float4*         coef = (float4*)ws;
    unsigned short* Wb   = (unsigned short*)(ws + COEF_B);
    i32x4*          Sg   = (i32x4*)(ws + COEF_B + W_B);           // 48 MB

    k_offsets<<<B_ * (L_ / 64), 512, 0, stream>>>(x, w1, b1, w2, b2,
                                                  weight, Wb, coef);
    k_sample<<<B_ * 32 * 24, 512, 0, stream>>>(x, coef, Sg);
    k_gemm<<<B_ * (L_ / 128), 512, 0, stream>>>(Wb, bias, Sg, out);
}

// Round 15
// 68.270 us; speedup vs baseline: 2.0034x; 1.1172x over previous
//
#include <hip/hip_runtime.h>
#include <hip/hip_bf16.h>
#include <math.h>

#define B_    8
#define C_    256
#define L_    4096
#define OCH_  256

typedef __attribute__((ext_vector_type(8)))  short bf16x8;
typedef __attribute__((ext_vector_type(16))) float f32x16;
typedef __attribute__((ext_vector_type(4)))  int   i32x4;

static __device__ __forceinline__ unsigned short bf16_rne(float f) {
    unsigned u = __float_as_uint(f);
    unsigned r = u + 0x7FFFu + ((u >> 16) & 1u);
    return (unsigned short)(r >> 16);
}

// ---------------------------------------------------------------------------
// K1: offset network + fused weight split (unchanged from R14).
// coef[(b*3+t)*L + l] = { d0, d1, bits(i0f2), 0 }:
//   sampled = x[i0f2]*d0 + x[i0f2+1]*d1  (clamp/validity/mod pre-folded)
// ---------------------------------------------------------------------------
__global__ __launch_bounds__(512) void k_offsets(
        const float* __restrict__ x,
        const float* __restrict__ w1, const float* __restrict__ b1,
        const float* __restrict__ w2, const float* __restrict__ b2,
        const float* __restrict__ W,  unsigned short* __restrict__ Wb,
        float4* __restrict__ coef) {
    __shared__ float sH[2][4][16][65];               // 33.3 KB [half][g][o][l]
    __shared__ float sOm[64][37];                    // 9.25 KB
    int tid  = threadIdx.x;
    int blk  = blockIdx.x;

    // ---- fused weight split: W[o][c][k] -> Wb[o][k*256+c] ----
    if (tid < 384) {
        int i = blk * 384 + tid;                     // o*768 + c*3 + k
        int k = i % 3;
        int c = (i / 3) & 255;
        int o = i / 768;
        Wb[o * 768 + k * 256 + c] = bf16_rne(W[i]);
    }

    int l    = tid & 63;
    int g    = (tid >> 6) & 3;
    int half = tid >> 8;
    int b    = blk & 7;                              // XCD affinity
    int l0   = (blk >> 3) << 6;
    int lg   = l0 + l;

    const float* xg = x + (size_t)b * C_ * L_ + (size_t)(g * 64 + half * 32) * L_ + lg;

    float h[16];
    #pragma unroll
    for (int o = 0; o < 16; ++o) h[o] = half ? 0.0f : b1[g * 16 + o];
    #pragma unroll 4
    for (int cg = 0; cg < 32; ++cg) {
        float xv = xg[(size_t)cg * L_];
        const float* w1p = w1 + (g * 16) * 64 + half * 32 + cg;
        #pragma unroll
        for (int o = 0; o < 16; ++o) h[o] = fmaf(xv, w1p[o * 64], h[o]);
    }
    #pragma unroll
    for (int o = 0; o < 16; ++o) sH[half][g][o][l] = h[o];
    __syncthreads();

    if (half == 0) {
        float om9[9];
        #pragma unroll
        for (int j = 0; j < 9; ++j) om9[j] = b2[g * 9 + j];
        #pragma unroll
        for (int o = 0; o < 16; ++o) {
            float a  = h[o] + sH[1][g][o][l];
            float hv = 0.5f * a * (1.0f + erff(a * 0.70710678118654752f));
            const float* w2p = w2 + g * 144 + o;     // w2[g][j][o]
            #pragma unroll
            for (int j = 0; j < 9; ++j) om9[j] = fmaf(hv, w2p[j * 16], om9[j]);
        }
        #pragma unroll
        for (int j = 0; j < 9; ++j) sOm[l][g * 9 + j] = om9[j];
    }
    __syncthreads();
    if (tid >= 64) return;

    float om[36];
    #pragma unroll
    for (int j = 0; j < 36; ++j) om[j] = sOm[tid][j];
    om[1] = 0.0f; om[3] = 0.0f; om[5] = 0.0f;
    float m = om[3];
    #pragma unroll
    for (int j = 4; j < 36; ++j) m = fmaxf(m, om[j]);
    float ssum = 0.0f;
    #pragma unroll
    for (int j = 3; j < 36; ++j) ssum += expf(om[j] - m);
    float inv = 1.0f / ssum;

    int lpos = l0 + tid;
    float base = -1.0f + 2.0f * (float)lpos / (float)(L_ - 1);
    #pragma unroll
    for (int t = 0; t < 3; ++t) {
        float mod  = expf(om[3 + t] - m) * inv;
        float off  = om[2 * t] * (2.0f / (float)L_);
        float grid = base + (-0.5f + 0.5f * (float)t) + off;
        float pp   = (grid + 1.0f) * 0.5f * (float)(L_ - 1);
        float fp   = floorf(pp);
        int i0 = (int)fp, i1 = i0 + 1;
        float w = pp - fp;
        float c0 = (i0 >= 0 && i0 < L_) ? (1.0f - w) * mod : 0.0f;
        float c1 = (i1 >= 0 && i1 < L_) ? w * mod : 0.0f;
        int i0c  = min(max(i0, 0), L_ - 1);
        int i1c  = min(max(i1, 0), L_ - 1);
        int i0f2 = min(max(i0, 0), L_ - 2);
        float d0 = (i0c == i0f2     ? c0 : 0.0f) + (i1c == i0f2     ? c1 : 0.0f);
        float d1 = (i0c == i0f2 + 1 ? c0 : 0.0f) + (i1c == i0f2 + 1 ? c1 : 0.0f);
        coef[((size_t)b * 3 + t) * L_ + lpos] =
            make_float4(d0, d1, __int_as_float(i0f2), 0.0f);
    }
}

// ---------------------------------------------------------------------------
// K2: FUSED sample + 1-pass bf16 MFMA GEMM. Tile 256o x 128l, grid 256
// (1 block/CU). Block 512 thr (8 waves); wave wv owns o-rows wv*32..+32,
// nf=4 col-frags. K=768 k-major, chunk 64 kk = 8 granule-slots x 128 l
// (16 KB/buffer, 2 buffers). Per chunk:
//   issue A(ch+1) regs + gather G(ch+1) (32 scalar x-loads, L2-resident)
//   -> sched_barrier -> 16 MFMAs on buf (gathers fly underneath)
//   -> pack G -> ds_write buf^1 (pre-barrier) -> __syncthreads.
// Staging map: thread (ls=tid&127, su=tid>>7) stages slots su, su+4.
// ds_write: wave = 1KB contiguous; ds_read_b128: 512B contiguous. No conflicts.
// ---------------------------------------------------------------------------
__global__ __launch_bounds__(512, 2) void k_conv(
        const float* __restrict__ x,
        const unsigned short* __restrict__ Wb,
        const float* __restrict__ bias,
        const float4* __restrict__ coef,
        float* __restrict__ out) {
    __shared__ i32x4 sS[2][8][128];                  // 32 KB

    const int tid  = threadIdx.x;
    const int lane = tid & 63;
    const int wv   = tid >> 6;                       // 0..7
    const int blk  = blockIdx.x;
    const int b    = blk & 7;                        // XCD affinity
    const int lt   = blk >> 3;                       // 0..31
    const int l0   = lt * 128;
    const int q    = lane >> 5;
    const int l31  = lane & 31;
    const int ls   = tid & 127;                      // staging column
    const int su   = tid >> 7;                       // staging sub-slot 0..3

    const float* xb = x + (size_t)b * (C_ * L_);

    // window coefficients for staging column l0+ls (scalars, no arrays)
    float4 cf0 = coef[((size_t)b * 3 + 0) * L_ + l0 + ls];
    float4 cf1 = coef[((size_t)b * 3 + 1) * L_ + l0 + ls];
    float4 cf2 = coef[((size_t)b * 3 + 2) * L_ + l0 + ls];
    const int   ib0 = __float_as_int(cf0.z), ib1 = __float_as_int(cf1.z), ib2 = __float_as_int(cf2.z);
    const float d00 = cf0.x, d01 = cf0.y;
    const float d10 = cf1.x, d11 = cf1.y;
    const float d20 = cf2.x, d21 = cf2.y;

    const unsigned short* WA = Wb + (size_t)(wv * 32 + l31) * 768 + q * 8;

    f32x16 acc0, acc1, acc2, acc3;
    #pragma unroll
    for (int i = 0; i < 16; ++i) { acc0[i] = 0.f; acc1[i] = 0.f; acc2[i] = 0.f; acc3[i] = 0.f; }

    bf16x8 aP0, aP1, aP2, aP3, aQ0, aQ1, aQ2, aQ3;
    float g0a[8], g1a[8], g0b[8], g1b[8];
    float dA0, dA1, dB0, dB1;

    // ---- gather helper (macro to keep everything in registers) ----
    #define GATHER(CH, SL, G0, G1, D0, D1) {                                  \
        int s_   = (CH) * 8 + (SL);                                           \
        int tap_ = s_ >> 5;                                                   \
        int c0_  = s_ * 8 - tap_ * 256;                                       \
        int ib_  = tap_ == 2 ? ib2 : tap_ == 1 ? ib1 : ib0;                   \
        D0 = tap_ == 2 ? d20 : tap_ == 1 ? d10 : d00;                         \
        D1 = tap_ == 2 ? d21 : tap_ == 1 ? d11 : d01;                         \
        const float* xp_ = xb + (size_t)c0_ * L_ + ib_;                       \
        _Pragma("unroll")                                                     \
        for (int j = 0; j < 8; ++j) {                                         \
            G0[j] = xp_[(size_t)j * L_];                                      \
            G1[j] = xp_[(size_t)j * L_ + 1];                                  \
        }                                                                     \
    }
    #define PACK(NBUF, SL, G0, G1, D0, D1) {                                  \
        union { unsigned short us[8]; i32x4 v; } ph_;                         \
        _Pragma("unroll")                                                     \
        for (int e = 0; e < 8; ++e)                                           \
            ph_.us[e] = bf16_rne(fmaf(G1[e], D1, G0[e] * D0));                \
        sS[NBUF][SL][ls] = ph_.v;                                             \
    }

    // ---- prologue: A(0), G(0), pack -> buf0, barrier ----
    aP0 = *(const bf16x8*)(WA);
    aP1 = *(const bf16x8*)(WA + 16);
    aP2 = *(const bf16x8*)(WA + 32);
    aP3 = *(const bf16x8*)(WA + 48);
    GATHER(0, su,     g0a, g1a, dA0, dA1)
    GATHER(0, su + 4, g0b, g1b, dB0, dB1)
    PACK(0, su,     g0a, g1a, dA0, dA1)
    PACK(0, su + 4, g0b, g1b, dB0, dB1)
    __syncthreads();

    #pragma unroll
    for (int ch = 0; ch < 12; ++ch) {
        const int buf = ch & 1;

        // ---- issue A(ch+1) + gathers G(ch+1); pinned above MFMA ----
        if (ch < 11) {
            const unsigned short* wn = WA + (ch + 1) * 64;
            aQ0 = *(const bf16x8*)(wn);
            aQ1 = *(const bf16x8*)(wn + 16);
            aQ2 = *(const bf16x8*)(wn + 32);
            aQ3 = *(const bf16x8*)(wn + 48);
            GATHER(ch + 1, su,     g0a, g1a, dA0, dA1)
            GATHER(ch + 1, su + 4, g0b, g1b, dB0, dB1)
        }
        __builtin_amdgcn_sched_barrier(0);

        // ---- MFMA phase: 4 ks x 4 nf (gathers fly underneath) ----
        #define KS_STEP(ks, AP) {                                            \
            const i32x4* bp = &sS[buf][(ks) * 2 + q][l31];                   \
            bf16x8 b0 = *(const bf16x8*)(bp);                                \
            bf16x8 b1 = *(const bf16x8*)(bp + 32);                           \
            bf16x8 b2 = *(const bf16x8*)(bp + 64);                           \
            bf16x8 b3 = *(const bf16x8*)(bp + 96);                           \
            __builtin_amdgcn_s_setprio(1);                                   \
            acc0 = __builtin_amdgcn_mfma_f32_32x32x16_bf16(AP, b0, acc0, 0, 0, 0); \
            acc1 = __builtin_amdgcn_mfma_f32_32x32x16_bf16(AP, b1, acc1, 0, 0, 0); \
            acc2 = __builtin_amdgcn_mfma_f32_32x32x16_bf16(AP, b2, acc2, 0, 0, 0); \
            acc3 = __builtin_amdgcn_mfma_f32_32x32x16_bf16(AP, b3, acc3, 0, 0, 0); \
            __builtin_amdgcn_s_setprio(0);                                   \
        }
        KS_STEP(0, aP0)
        KS_STEP(1, aP1)
        KS_STEP(2, aP2)
        KS_STEP(3, aP3)
        #undef KS_STEP
        __builtin_amdgcn_sched_barrier(0);

        // ---- pack + ds_write into buf^1 (pre-barrier), rotate A ----
        if (ch < 11) {
            PACK(buf ^ 1, su,     g0a, g1a, dA0, dA1)
            PACK(buf ^ 1, su + 4, g0b, g1b, dB0, dB1)
            aP0 = aQ0; aP1 = aQ1; aP2 = aQ2; aP3 = aQ3;
        }
        __syncthreads();
    }
    #undef GATHER
    #undef PACK

    // epilogue: bias + store. D: col=lane&31, row=(reg&3)+8*(reg>>2)+4*q
    #pragma unroll
    for (int reg = 0; reg < 16; ++reg) {
        int rr = (reg & 3) + 8 * (reg >> 2) + 4 * q;
        int o  = wv * 32 + rr;
        float bv = bias[o];
        float* op = out + ((size_t)b * 256 + o) * L_ + l0 + l31;
        op[0]  = acc0[reg] + bv;
        op[32] = acc1[reg] + bv;
        op[64] = acc2[reg] + bv;
        op[96] = acc3[reg] + bv;
    }
}

// ---------------------------------------------------------------------------
extern "C" void kernel_launch(void* const* d_in, const int* in_sizes, int n_in,
                              void* d_out, int out_size, void* d_ws, size_t ws_size,
                              hipStream_t stream) {
    const float* x      = (const float*)d_in[0];
    const float* weight = (const float*)d_in[1];
    const float* bias   = (const float*)d_in[2];
    const float* w1     = (const float*)d_in[3];
    const float* b1     = (const float*)d_in[4];
    const float* w2     = (const float*)d_in[5];
    const float* b2     = (const float*)d_in[6];
    float* out = (float*)d_out;

    const size_t COEF_B = (size_t)B_ * 3 * L_ * sizeof(float4);   // 1.5 MB
    char* ws = (char*)d_ws;
    float4*         coef = (float4*)ws;
    unsigned short* Wb   = (unsigned short*)(ws + COEF_B);        // 384 KB

    k_offsets<<<B_ * (L_ / 64), 512, 0, stream>>>(x, w1, b1, w2, b2,
                                                  weight, Wb, coef);
    k_conv<<<B_ * (L_ / 128), 512, 0, stream>>>(x, Wb, bias, coef, out);
}